// Round 10
// baseline (963.778 us; speedup 1.0000x reference)
//
#include <hip/hip_runtime.h>
#include <hip/hip_cooperative_groups.h>
#include <stdint.h>

namespace cg = cooperative_groups;

#define N0c 1200000
#define N1c 120000
#define N2c 12000
#define E0c 1200000
#define E1c 120000
#define NB0 118   // ceil(N1c/1024)
#define NB1 12    // ceil(N2c/1024)
#define N1pad 120064
#define N2pad 12032
#define ROWB 80   // bytes per 32-col K-row in tiled layout (64 data + 16 pad)
#define ROWU 40   // u16 per K-row
#define CSRB 1024 // cooperative CSR blocks (<= co-residency capacity 2048)

typedef short short8 __attribute__((ext_vector_type(8)));
typedef float f32x4 __attribute__((ext_vector_type(4)));
typedef unsigned short u16;

__device__ __forceinline__ u16 f2bf(float f) {
    union { float f; unsigned u; } v; v.f = f;
    unsigned r = v.u + 0x7FFFu + ((v.u >> 16) & 1u);
    return (u16)(r >> 16);
}

__device__ __forceinline__ void gload16(const char* g, char* l) {
    __builtin_amdgcn_global_load_lds(
        (const __attribute__((address_space(1))) void*)g,
        (__attribute__((address_space(3))) void*)l, 16, 0, 0);
}

// ---------------- fused CSR build (cooperative): zero -> hist+wcat ->
// scanA -> scanC(+scanB folded) -> scat. XCD-partitioned counts: part =
// blockIdx&7 identical in hist and scat phases -> counters self-restore.
__global__ void k_csr(const int* __restrict__ src0, const int* __restrict__ dst0,
                      const int* __restrict__ src1, const int* __restrict__ dst1,
                      int* __restrict__ c0, int* __restrict__ c1,
                      int* __restrict__ partials,
                      int* __restrict__ rs0, int* __restrict__ rs1,
                      int* __restrict__ bs0, int* __restrict__ bs1,
                      int* __restrict__ eidx0, int* __restrict__ eidx1,
                      u16* __restrict__ Bt0, const float* __restrict__ Wl0,
                      const float* __restrict__ Wr0, u16* __restrict__ Bt1,
                      const float* __restrict__ Wl1, const float* __restrict__ Wr1) {
    cg::grid_group grid = cg::this_grid();
    __shared__ int sh[256];
    __shared__ int baseSh;
    const int bid = blockIdx.x, tid = threadIdx.x;
    const int part = bid & 7;
    const int gstep = CSRB * 256;
    const int g0 = bid * 256 + tid;

    // phase 0: zero the count arrays (ws is poisoned 0xAA on first replay)
    for (int i = g0; i < 8 * N1c; i += gstep) c0[i] = 0;
    for (int i = g0; i < 8 * N2c; i += gstep) c1[i] = 0;
    grid.sync();

    // phase 1: histogram (XCD-local atomics) + weight convert (independent)
    for (int i = g0; i < E0c; i += gstep) atomicAdd(&c0[part * N1c + dst0[i]], 1);
    for (int i = g0; i < E1c; i += gstep) atomicAdd(&c1[part * N2c + dst1[i]], 1);
    for (int i = g0; i < 256 * 512; i += gstep) {
        int c = i >> 9, k = i & 511;
        float v = (k < 256) ? Wl0[c * 256 + k] : Wr0[c * 256 + (k - 256)];
        Bt0[((size_t)(k >> 5) * 256 + c) * ROWU + (k & 31)] = f2bf(v);
    }
    for (int j = g0; j < 128 * 512; j += gstep) {
        int c = j >> 9, k = j & 511;
        float v = 0.f;
        if (c < 64) v = (k < 256) ? Wl1[c * 256 + k] : Wr1[c * 256 + (k - 256)];
        Bt1[j] = f2bf(v);
    }
    grid.sync();

    // phase 2: per-block totals (scanA) — blocks 0..NB0+NB1-1
    if (bid < NB0 + NB1) {
        int hop = bid >= NB0;
        int blk = hop ? bid - NB0 : bid;
        const int* c = hop ? c1 : c0;
        int n = hop ? N2c : N1c;
        int d0 = blk * 1024 + tid * 4;
        int tsum = 0;
#pragma unroll
        for (int j = 0; j < 4; ++j) {
            int d = d0 + j;
            if (d < n)
#pragma unroll
                for (int k = 0; k < 8; ++k) tsum += c[k * n + d];
        }
        sh[tid] = tsum;
        __syncthreads();
        for (int ofs = 128; ofs > 0; ofs >>= 1) {
            if (tid < ofs) sh[tid] += sh[tid + ofs];
            __syncthreads();
        }
        if (tid == 0) partials[bid] = sh[0];
    }
    grid.sync();

    // phase 3: rebuild rs[d] + per-copy bases bs[k][d] (scanB folded in)
    if (bid < NB0 + NB1) {
        int hop = bid >= NB0;
        int blk = hop ? bid - NB0 : bid;
        const int* c = hop ? c1 : c0;
        int* rs = hop ? rs1 : rs0;
        int* bs = hop ? bs1 : bs0;
        int n = hop ? N2c : N1c;
        int segBase = hop ? NB0 : 0;

        sh[tid] = (tid < blk) ? partials[segBase + tid] : 0;
        __syncthreads();
        for (int ofs = 128; ofs > 0; ofs >>= 1) {
            if (tid < ofs) sh[tid] += sh[tid + ofs];
            __syncthreads();
        }
        if (tid == 0) baseSh = sh[0];
        __syncthreads();

        int d0 = blk * 1024 + tid * 4;
        int cv[4][8];
        int tsum = 0;
#pragma unroll
        for (int j = 0; j < 4; ++j)
#pragma unroll
            for (int k = 0; k < 8; ++k) {
                int d = d0 + j;
                int v = (d < n) ? c[k * n + d] : 0;
                cv[j][k] = v; tsum += v;
            }
        sh[tid] = tsum; __syncthreads();
        for (int ofs = 1; ofs < 256; ofs <<= 1) {
            int t = tid >= ofs ? sh[tid - ofs] : 0;
            __syncthreads();
            sh[tid] += t;
            __syncthreads();
        }
        int run = baseSh + sh[tid] - tsum;
#pragma unroll
        for (int j = 0; j < 4; ++j) {
            int d = d0 + j;
            if (d < n) {
                rs[d] = run;
#pragma unroll
                for (int k = 0; k < 8; ++k) { bs[k * n + d] = run; run += cv[j][k]; }
            }
        }
        if (blk == 0 && tid == 0) {
            if (hop) rs1[N2c] = E1c; else rs0[N1c] = E0c;
        }
    }
    grid.sync();

    // phase 4: scatter (same part mapping as phase 1 -> counters return to 0)
    for (int i = g0; i < E0c; i += gstep) {
        int d = dst0[i];
        int off = atomicSub(&c0[part * N1c + d], 1) - 1;
        eidx0[bs0[part * N1c + d] + off] = src0[i];
    }
    for (int i = g0; i < E1c; i += gstep) {
        int d = dst1[i];
        int off = atomicSub(&c1[part * N2c + d], 1) - 1;
        eidx1[bs1[part * N2c + d] + off] = src1[i];
    }
}

// ---------------- agg layer 0: mean gather only -> K-tiled A0 [kt=8] --------
// nontemporal gather: 1.23GB stream >> L2, caching only pollutes (r7 vs r8:
// removing nt cost ~50us)
__global__ void k_agg0(const float* __restrict__ x, const int* __restrict__ eidx,
                       const int* __restrict__ rs, u16* __restrict__ A, int ntgt) {
    int w = (int)((blockIdx.x * blockDim.x + threadIdx.x) >> 6);
    int lane = threadIdx.x & 63;
    if (w >= ntgt) return;
    int s = rs[w], e = rs[w + 1];
    float a0 = 0.f, a1 = 0.f, a2 = 0.f, a3 = 0.f;
    int i = s;
    for (; i + 8 <= e; i += 8) {  // 8 independent 1KB row loads in flight
        f32x4 v[8];
#pragma unroll
        for (int u = 0; u < 8; ++u)
            v[u] = __builtin_nontemporal_load(
                ((const f32x4*)(x + (long)eidx[i + u] * 256)) + lane);
#pragma unroll
        for (int u = 0; u < 8; ++u) {
            a0 += v[u][0]; a1 += v[u][1]; a2 += v[u][2]; a3 += v[u][3];
        }
    }
    for (; i + 2 <= e; i += 2) {
        f32x4 v0 = __builtin_nontemporal_load(
            ((const f32x4*)(x + (long)eidx[i] * 256)) + lane);
        f32x4 v1 = __builtin_nontemporal_load(
            ((const f32x4*)(x + (long)eidx[i + 1] * 256)) + lane);
        a0 += v0[0] + v1[0]; a1 += v0[1] + v1[1];
        a2 += v0[2] + v1[2]; a3 += v0[3] + v1[3];
    }
    if (i < e) {
        f32x4 v = __builtin_nontemporal_load(
            ((const f32x4*)(x + (long)eidx[i] * 256)) + lane);
        a0 += v[0]; a1 += v[1]; a2 += v[2]; a3 += v[3];
    }
    int c = e - s; if (c < 1) c = 1;
    float sc = 1.f / (float)c;
    int kt = lane >> 3;
    int cu = (lane & 7) * 4;
    ushort4 oa;
    oa.x = f2bf(a0 * sc); oa.y = f2bf(a1 * sc); oa.z = f2bf(a2 * sc); oa.w = f2bf(a3 * sc);
    *(ushort4*)(A + ((size_t)kt * N1pad + w) * ROWU + cu) = oa;
}

// ---------------- agg layer 1: mean gather -> row-major A1 [w][512] ---------
__global__ void k_agg1(const u16* __restrict__ hsrc, const int* __restrict__ eidx,
                       const int* __restrict__ rs, u16* __restrict__ A, int ntgt) {
    int w = (int)((blockIdx.x * blockDim.x + threadIdx.x) >> 6);
    int lane = threadIdx.x & 63;
    if (w >= ntgt) return;
    int s = rs[w], e = rs[w + 1];
    float a0 = 0.f, a1 = 0.f, a2 = 0.f, a3 = 0.f;
    auto acc4 = [&](ushort4 v) {
        union { unsigned u; float f; } c0, c1, c2, c3;
        c0.u = (unsigned)v.x << 16; c1.u = (unsigned)v.y << 16;
        c2.u = (unsigned)v.z << 16; c3.u = (unsigned)v.w << 16;
        a0 += c0.f; a1 += c1.f; a2 += c2.f; a3 += c3.f;
    };
    int i = s;
    for (; i + 4 <= e; i += 4) {
        ushort4 v0 = ((const ushort4*)(hsrc + (long)eidx[i] * 256))[lane];
        ushort4 v1 = ((const ushort4*)(hsrc + (long)eidx[i + 1] * 256))[lane];
        ushort4 v2 = ((const ushort4*)(hsrc + (long)eidx[i + 2] * 256))[lane];
        ushort4 v3 = ((const ushort4*)(hsrc + (long)eidx[i + 3] * 256))[lane];
        acc4(v0); acc4(v1); acc4(v2); acc4(v3);
    }
    for (; i < e; ++i) {
        ushort4 v = ((const ushort4*)(hsrc + (long)eidx[i] * 256))[lane];
        acc4(v);
    }
    int c = e - s; if (c < 1) c = 1;
    float sc = 1.f / (float)c;
    ushort4 o;
    o.x = f2bf(a0 * sc); o.y = f2bf(a1 * sc); o.z = f2bf(a2 * sc); o.w = f2bf(a3 * sc);
    *(ushort4*)(A + (long)w * 512 + lane * 4) = o;
    ushort4 sv = ((const ushort4*)(hsrc + (long)w * 256))[lane];
    *(ushort4*)(A + (long)w * 512 + 256 + lane * 4) = sv;
}

// ---------------- GEMM0: agg half via gload_lds, self half direct from x ----
// 512 thr (8 waves, 2x4), tile 128x256, K=512 in 16 steps of 32. (r7 version)
__global__ __launch_bounds__(512)
void k_gemm0(const u16* __restrict__ A0, const float* __restrict__ x,
             const u16* __restrict__ Bt, const float* __restrict__ bias,
             u16* __restrict__ outp) {
    __shared__ int4 Lbuf[2 * 30720 / 16];
    char* L = (char*)Lbuf;
    const int tid = threadIdx.x;
    const int lane = tid & 63, wid = tid >> 6;
    const int wm = wid >> 2, wn = wid & 3;
    const long m0 = (long)blockIdx.x * 128;

    f32x4 acc[4][4];
#pragma unroll
    for (int i = 0; i < 4; ++i)
#pragma unroll
        for (int j = 0; j < 4; ++j) acc[i][j] = (f32x4){0.f, 0.f, 0.f, 0.f};

    const char* Abase = (const char*)A0 + m0 * ROWB;
    const char* Bbase = (const char*)Bt;
    const int srow = tid >> 2, scq = tid & 3;  // self-half reg-stage mapping

    auto stage = [&](int buf, int kt) {
        char* lb = L + buf * 30720;
        const char* gb = Bbase + (size_t)kt * (256 * ROWB);
        if (kt < 8) {
            const char* ga = Abase + (size_t)kt * ((size_t)N1pad * ROWB);
#pragma unroll
            for (int c0 = 0; c0 < 4; ++c0) {
                int c = wid + c0 * 8;
                if (c < 30) {
                    const char* g = (c < 10) ? (ga + c * 1024) : (gb + (c - 10) * 1024);
                    gload16(g + lane * 16, lb + c * 1024);
                }
            }
        } else {
#pragma unroll
            for (int c0 = 0; c0 < 3; ++c0) {
                int c = wid + c0 * 8;
                if (c < 20) gload16(gb + c * 1024 + lane * 16, lb + 10240 + c * 1024);
            }
            // self half: 128 rows x 32 f32 from x, convert to bf16, ds_write
            const f32x4* p =
                (const f32x4*)(x + (m0 + srow) * 256 + (kt - 8) * 32 + scq * 8);
            f32x4 v0 = p[0], v1 = p[1];
            ushort4 h0, h1;
            h0.x = f2bf(v0[0]); h0.y = f2bf(v0[1]); h0.z = f2bf(v0[2]); h0.w = f2bf(v0[3]);
            h1.x = f2bf(v1[0]); h1.y = f2bf(v1[1]); h1.z = f2bf(v1[2]); h1.w = f2bf(v1[3]);
            ushort4* d = (ushort4*)(lb + srow * ROWB + scq * 16);
            d[0] = h0; d[1] = h1;
        }
    };

    stage(0, 0);
    const int rr = lane & 15, gg = lane >> 4;
    for (int ks = 0; ks < 16; ++ks) {
        int cur = ks & 1;
        __syncthreads();  // buf[cur] staged (vmcnt+lgkm drained); buf[cur^1] free
        if (ks + 1 < 16) stage(cur ^ 1, ks + 1);  // overlaps MFMA below
        const char* lb = L + cur * 30720;
        short8 af[4], bv[4];
#pragma unroll
        for (int f = 0; f < 4; ++f) {
            af[f] = *(const short8*)(lb + (wm * 64 + f * 16 + rr) * ROWB + gg * 16);
            bv[f] = *(const short8*)(lb + 10240 + (wn * 64 + f * 16 + rr) * ROWB + gg * 16);
        }
#pragma unroll
        for (int i = 0; i < 4; ++i)
#pragma unroll
            for (int j = 0; j < 4; ++j)
                acc[i][j] =
                    __builtin_amdgcn_mfma_f32_16x16x32_bf16(af[i], bv[j], acc[i][j], 0, 0, 0);
    }

    // epilogue: bias + relu + bf16 store (D row=(lane>>4)*4+q, col=lane&15)
#pragma unroll
    for (int j = 0; j < 4; ++j) {
        int col = wn * 64 + j * 16 + rr;
        float bvl = bias[col];
#pragma unroll
        for (int i = 0; i < 4; ++i) {
            long row = m0 + wm * 64 + i * 16 + gg * 4;
#pragma unroll
            for (int q = 0; q < 4; ++q) {
                long r = row + q;
                if (r < N1c) {
                    float v = acc[i][j][q] + bvl;
                    v = v > 0.f ? v : 0.f;
                    outp[r * 256 + col] = f2bf(v);
                }
            }
        }
    }
}

// ---------------- GEMM1 + fused log_softmax -> d_out ------------------------
// 256 thr (4 waves 2x2), tile 128x128 (cols 64..127 are zero pad), K=512.
__global__ __launch_bounds__(256)
void k_gemm1(const u16* __restrict__ A, const u16* __restrict__ Bt,
             const float* __restrict__ bias, float* __restrict__ outp) {
    __shared__ u16 As[128 * 40];
    __shared__ u16 Bs[128 * 40];
    const int tid = threadIdx.x;
    const int lane = tid & 63, wid = tid >> 6;
    const int wm = wid >> 1, wn = wid & 1;
    const long m0 = (long)blockIdx.x * 128;
    const int sar = tid >> 1, sac = (tid & 1) * 16;

    f32x4 acc[4][4];
#pragma unroll
    for (int i = 0; i < 4; ++i)
#pragma unroll
        for (int j = 0; j < 4; ++j) acc[i][j] = (f32x4){0.f, 0.f, 0.f, 0.f};

    int4 ra[2]; int4 rb[2];
    auto load_tile = [&](int ks) {
        int k0 = ks * 32;
        const int4* p = (const int4*)(A + (m0 + sar) * 512 + k0 + sac);
        ra[0] = p[0]; ra[1] = p[1];
        const int4* q = (const int4*)(Bt + (long)sar * 512 + k0 + sac);
        rb[0] = q[0]; rb[1] = q[1];
    };
    auto write_tile = [&]() {
        int4* da = (int4*)(As + sar * 40 + sac);
        da[0] = ra[0]; da[1] = ra[1];
        int4* db = (int4*)(Bs + sar * 40 + sac);
        db[0] = rb[0]; db[1] = rb[1];
    };

    load_tile(0);
    for (int ks = 0; ks < 16; ++ks) {
        __syncthreads();
        write_tile();
        __syncthreads();
        if (ks + 1 < 16) load_tile(ks + 1);
        short8 af[4], bv[4];
        const int rr = lane & 15, gg = lane >> 4;
#pragma unroll
        for (int f = 0; f < 4; ++f) {
            af[f] = *(const short8*)(As + (wm * 64 + f * 16 + rr) * 40 + gg * 8);
            bv[f] = *(const short8*)(Bs + (wn * 64 + f * 16 + rr) * 40 + gg * 8);
        }
#pragma unroll
        for (int i = 0; i < 4; ++i)
#pragma unroll
            for (int j = 0; j < 4; ++j)
                acc[i][j] =
                    __builtin_amdgcn_mfma_f32_16x16x32_bf16(af[i], bv[j], acc[i][j], 0, 0, 0);
    }

    // epilogue: only wn==0 waves hold real cols (0..63); bias + log_softmax
    const int rr = lane & 15, gg = lane >> 4;
    if (wn == 0) {
#pragma unroll
        for (int i = 0; i < 4; ++i) {
#pragma unroll
            for (int q = 0; q < 4; ++q) {
                long r = m0 + wm * 64 + i * 16 + gg * 4 + q;
                float v[4];
#pragma unroll
                for (int j = 0; j < 4; ++j) v[j] = acc[i][j][q] + bias[j * 16 + rr];
                float mx = fmaxf(fmaxf(v[0], v[1]), fmaxf(v[2], v[3]));
#pragma unroll
                for (int m = 1; m < 16; m <<= 1) mx = fmaxf(mx, __shfl_xor(mx, m, 16));
                float se = __expf(v[0] - mx) + __expf(v[1] - mx) +
                           __expf(v[2] - mx) + __expf(v[3] - mx);
#pragma unroll
                for (int m = 1; m < 16; m <<= 1) se += __shfl_xor(se, m, 16);
                float ln = __logf(se);
                if (r < N2c) {
#pragma unroll
                    for (int j = 0; j < 4; ++j)
                        outp[r * 64 + j * 16 + rr] = v[j] - mx - ln;
                }
            }
        }
    }
}

extern "C" void kernel_launch(void* const* d_in, const int* in_sizes, int n_in,
                              void* d_out, int out_size, void* d_ws, size_t ws_size,
                              hipStream_t stream) {
    const float* x   = (const float*)d_in[0];
    const int* src0  = (const int*)d_in[1];
    const int* dst0  = (const int*)d_in[2];
    const int* src1  = (const int*)d_in[3];
    const int* dst1  = (const int*)d_in[4];
    const float* Wl0 = (const float*)d_in[5];
    const float* b0  = (const float*)d_in[6];
    const float* Wr0 = (const float*)d_in[7];
    const float* Wl1 = (const float*)d_in[8];
    const float* b1  = (const float*)d_in[9];
    const float* Wr1 = (const float*)d_in[10];

    char* base = (char*)d_ws;
    size_t off = 0;
    auto alloc = [&](size_t bytes) -> void* {
        off = (off + 255) & ~(size_t)255;
        void* p = base + off;
        off += bytes;
        return p;
    };
    int* c0       = (int*)alloc((size_t)8 * N1c * 4);
    int* c1       = (int*)alloc((size_t)8 * N2c * 4);
    int* bs0      = (int*)alloc((size_t)8 * N1c * 4);
    int* bs1      = (int*)alloc((size_t)8 * N2c * 4);
    int* rs0      = (int*)alloc((size_t)(N1c + 1) * 4);
    int* rs1      = (int*)alloc((size_t)(N2c + 1) * 4);
    int* partials = (int*)alloc((size_t)(NB0 + NB1) * 4);
    int* eidx0    = (int*)alloc((size_t)E0c * 4);
    int* eidx1    = (int*)alloc((size_t)E1c * 4);
    u16* A0       = (u16*)alloc((size_t)8 * N1pad * ROWU * 2);   // agg half only
    u16* hbuf     = (u16*)alloc((size_t)N1pad * 256 * 2);
    u16* A1       = (u16*)alloc((size_t)N2pad * 512 * 2);
    u16* Bt0      = (u16*)alloc((size_t)16 * 256 * ROWU * 2);    // K-tiled
    u16* Bt1      = (u16*)alloc((size_t)128 * 512 * 2);

    // fused cooperative CSR build (zero+hist+wcat+scan+scatter, 1 dispatch)
    void* args[] = {
        (void*)&src0, (void*)&dst0, (void*)&src1, (void*)&dst1,
        (void*)&c0, (void*)&c1, (void*)&partials,
        (void*)&rs0, (void*)&rs1, (void*)&bs0, (void*)&bs1,
        (void*)&eidx0, (void*)&eidx1,
        (void*)&Bt0, (void*)&Wl0, (void*)&Wr0,
        (void*)&Bt1, (void*)&Wl1, (void*)&Wr1,
    };
    (void)hipLaunchCooperativeKernel((const void*)k_csr, dim3(CSRB), dim3(256),
                                     args, 0, stream);

    // layer 0: gather (agg half) then GEMM (self read direct from x)
    k_agg0<<<(N1c + 3) / 4, 256, 0, stream>>>(x, eidx0, rs0, A0, N1c);
    k_gemm0<<<N1pad / 128, 512, 0, stream>>>(A0, x, Bt0, b0, hbuf);

    // layer 1: gather then GEMM + fused log_softmax
    k_agg1<<<(N2c + 3) / 4, 256, 0, stream>>>(hbuf, eidx1, rs1, A1, N2c);
    k_gemm1<<<N2pad / 128, 256, 0, stream>>>(A1, Bt1, b1, (float*)d_out);
}

// Round 11
// 527.819 us; speedup vs baseline: 1.8260x; 1.8260x over previous
//
#include <hip/hip_runtime.h>
#include <stdint.h>

#define N0c 1200000
#define N1c 120000
#define N2c 12000
#define E0c 1200000
#define E1c 120000
#define NB0 118   // ceil(N1c/1024)
#define NB1 12    // ceil(N2c/1024)
#define N1pad 120064
#define N2pad 12032
#define ROWB 80   // bytes per 32-col K-row in tiled layout (64 data + 16 pad)
#define ROWU 40   // u16 per K-row
#define HB 5157   // hist blocks = ceil((E0c+E1c)/256)
#define WCB 768   // wcat blocks = (256*512 + 128*512)/256

typedef short short8 __attribute__((ext_vector_type(8)));
typedef float f32x4 __attribute__((ext_vector_type(4)));
typedef unsigned short u16;

__device__ __forceinline__ u16 f2bf(float f) {
    union { float f; unsigned u; } v; v.f = f;
    unsigned r = v.u + 0x7FFFu + ((v.u >> 16) & 1u);
    return (u16)(r >> 16);
}

__device__ __forceinline__ void gload16(const char* g, char* l) {
    __builtin_amdgcn_global_load_lds(
        (const __attribute__((address_space(1))) void*)g,
        (__attribute__((address_space(3))) void*)l, 16, 0, 0);
}

// ---------------- CSR hist + weight convert (independent work, one kernel) --
// Bt0: K-tiled [kt=16][256 ch][ROWU]; Bt1: row-major [128][512], rows>=64 zero
__global__ void k_hist(const int* __restrict__ dst0, const int* __restrict__ dst1,
                       int* __restrict__ c0, int* __restrict__ c1,
                       u16* __restrict__ Bt0, const float* __restrict__ Wl0,
                       const float* __restrict__ Wr0, u16* __restrict__ Bt1,
                       const float* __restrict__ Wl1, const float* __restrict__ Wr1) {
    if (blockIdx.x < HB) {
        int i = blockIdx.x * 256 + threadIdx.x;
        int part = blockIdx.x & 7;
        if (i < E0c) atomicAdd(&c0[part * N1c + dst0[i]], 1);
        else if (i < E0c + E1c) atomicAdd(&c1[part * N2c + dst1[i - E0c]], 1);
    } else {
        int i = (blockIdx.x - HB) * 256 + threadIdx.x;
        if (i < 256 * 512) {
            int c = i >> 9, k = i & 511;
            float v = (k < 256) ? Wl0[c * 256 + k] : Wr0[c * 256 + (k - 256)];
            Bt0[((size_t)(k >> 5) * 256 + c) * ROWU + (k & 31)] = f2bf(v);
        } else {
            int j = i - 256 * 512;
            int c = j >> 9, k = j & 511;
            float v = 0.f;
            if (c < 64) v = (k < 256) ? Wl1[c * 256 + k] : Wr1[c * 256 + (k - 256)];
            Bt1[j] = f2bf(v);
        }
    }
}

// per-block totals of sum over 8 copies (raw, unscanned)
__global__ void k_scanA(const int* __restrict__ c0, const int* __restrict__ c1,
                        int* __restrict__ partials) {
    __shared__ int sh[256];
    int hop = blockIdx.x >= NB0;
    int blk = hop ? blockIdx.x - NB0 : blockIdx.x;
    const int* c = hop ? c1 : c0;
    int n = hop ? N2c : N1c;
    int d0 = blk * 1024 + threadIdx.x * 4;
    int tsum = 0;
#pragma unroll
    for (int j = 0; j < 4; ++j) {
        int d = d0 + j;
        if (d < n)
#pragma unroll
            for (int k = 0; k < 8; ++k) tsum += c[k * n + d];
    }
    sh[threadIdx.x] = tsum;
    __syncthreads();
    for (int ofs = 128; ofs > 0; ofs >>= 1) {
        if (threadIdx.x < ofs) sh[threadIdx.x] += sh[threadIdx.x + ofs];
        __syncthreads();
    }
    if (threadIdx.x == 0) partials[blockIdx.x] = sh[0];
}

// rebuild rs[d] + per-copy segment bases bs[k][d]; block base computed
// in-block from raw partials (scanB folded in: 130 L2-resident ints)
__global__ void k_scanC(const int* __restrict__ c0, const int* __restrict__ c1,
                        const int* __restrict__ partials, int* __restrict__ rs0,
                        int* __restrict__ rs1, int* __restrict__ bs0,
                        int* __restrict__ bs1) {
    __shared__ int sh[256];
    __shared__ int baseSh;
    int hop = blockIdx.x >= NB0;
    int blk = hop ? blockIdx.x - NB0 : blockIdx.x;
    const int* c = hop ? c1 : c0;
    int* rs = hop ? rs1 : rs0;
    int* bs = hop ? bs1 : bs0;
    int n = hop ? N2c : N1c;
    int segBase = hop ? NB0 : 0;
    int tid = threadIdx.x;

    // block base = sum of my segment's partials strictly before blk
    sh[tid] = (tid < blk) ? partials[segBase + tid] : 0;
    __syncthreads();
    for (int ofs = 128; ofs > 0; ofs >>= 1) {
        if (tid < ofs) sh[tid] += sh[tid + ofs];
        __syncthreads();
    }
    if (tid == 0) baseSh = sh[0];
    __syncthreads();

    int d0 = blk * 1024 + tid * 4;
    int cv[4][8];
    int tsum = 0;
#pragma unroll
    for (int j = 0; j < 4; ++j)
#pragma unroll
        for (int k = 0; k < 8; ++k) {
            int d = d0 + j;
            int v = (d < n) ? c[k * n + d] : 0;
            cv[j][k] = v; tsum += v;
        }
    sh[tid] = tsum; __syncthreads();
    for (int ofs = 1; ofs < 256; ofs <<= 1) {
        int t = tid >= ofs ? sh[tid - ofs] : 0;
        __syncthreads();
        sh[tid] += t;
        __syncthreads();
    }
    int run = baseSh + sh[tid] - tsum;
#pragma unroll
    for (int j = 0; j < 4; ++j) {
        int d = d0 + j;
        if (d < n) {
            rs[d] = run;
#pragma unroll
            for (int k = 0; k < 8; ++k) { bs[k * n + d] = run; run += cv[j][k]; }
        }
    }
    if (blk == 0 && tid == 0) {
        if (hop) rs1[N2c] = E1c; else rs0[N1c] = E0c;
    }
}

__global__ void k_scat(const int* __restrict__ src0, const int* __restrict__ dst0,
                       const int* __restrict__ src1, const int* __restrict__ dst1,
                       int* __restrict__ c0, int* __restrict__ c1,
                       const int* __restrict__ bs0, const int* __restrict__ bs1,
                       int* __restrict__ eidx0, int* __restrict__ eidx1) {
    int i = blockIdx.x * 256 + threadIdx.x;
    int part = blockIdx.x & 7;
    if (i < E0c) {
        int d = dst0[i];
        int off = atomicSub(&c0[part * N1c + d], 1) - 1;
        eidx0[bs0[part * N1c + d] + off] = src0[i];
    } else if (i < E0c + E1c) {
        int j = i - E0c;
        int d = dst1[j];
        int off = atomicSub(&c1[part * N2c + d], 1) - 1;
        eidx1[bs1[part * N2c + d] + off] = src1[j];
    }
}

// ---------------- agg layer 0: mean gather only -> K-tiled A0 [kt=8] --------
// nontemporal gather: 1.23GB stream >> L2, caching only pollutes (r7 vs r8:
// removing nt cost ~50us)
__global__ void k_agg0(const float* __restrict__ x, const int* __restrict__ eidx,
                       const int* __restrict__ rs, u16* __restrict__ A, int ntgt) {
    int w = (int)((blockIdx.x * blockDim.x + threadIdx.x) >> 6);
    int lane = threadIdx.x & 63;
    if (w >= ntgt) return;
    int s = rs[w], e = rs[w + 1];
    float a0 = 0.f, a1 = 0.f, a2 = 0.f, a3 = 0.f;
    int i = s;
    for (; i + 8 <= e; i += 8) {  // 8 independent 1KB row loads in flight
        f32x4 v[8];
#pragma unroll
        for (int u = 0; u < 8; ++u)
            v[u] = __builtin_nontemporal_load(
                ((const f32x4*)(x + (long)eidx[i + u] * 256)) + lane);
#pragma unroll
        for (int u = 0; u < 8; ++u) {
            a0 += v[u][0]; a1 += v[u][1]; a2 += v[u][2]; a3 += v[u][3];
        }
    }
    for (; i + 2 <= e; i += 2) {
        f32x4 v0 = __builtin_nontemporal_load(
            ((const f32x4*)(x + (long)eidx[i] * 256)) + lane);
        f32x4 v1 = __builtin_nontemporal_load(
            ((const f32x4*)(x + (long)eidx[i + 1] * 256)) + lane);
        a0 += v0[0] + v1[0]; a1 += v0[1] + v1[1];
        a2 += v0[2] + v1[2]; a3 += v0[3] + v1[3];
    }
    if (i < e) {
        f32x4 v = __builtin_nontemporal_load(
            ((const f32x4*)(x + (long)eidx[i] * 256)) + lane);
        a0 += v[0]; a1 += v[1]; a2 += v[2]; a3 += v[3];
    }
    int c = e - s; if (c < 1) c = 1;
    float sc = 1.f / (float)c;
    int kt = lane >> 3;
    int cu = (lane & 7) * 4;
    ushort4 oa;
    oa.x = f2bf(a0 * sc); oa.y = f2bf(a1 * sc); oa.z = f2bf(a2 * sc); oa.w = f2bf(a3 * sc);
    *(ushort4*)(A + ((size_t)kt * N1pad + w) * ROWU + cu) = oa;
}

// ---------------- agg layer 1: mean gather -> row-major A1 [w][512] ---------
__global__ void k_agg1(const u16* __restrict__ hsrc, const int* __restrict__ eidx,
                       const int* __restrict__ rs, u16* __restrict__ A, int ntgt) {
    int w = (int)((blockIdx.x * blockDim.x + threadIdx.x) >> 6);
    int lane = threadIdx.x & 63;
    if (w >= ntgt) return;
    int s = rs[w], e = rs[w + 1];
    float a0 = 0.f, a1 = 0.f, a2 = 0.f, a3 = 0.f;
    auto acc4 = [&](ushort4 v) {
        union { unsigned u; float f; } c0, c1, c2, c3;
        c0.u = (unsigned)v.x << 16; c1.u = (unsigned)v.y << 16;
        c2.u = (unsigned)v.z << 16; c3.u = (unsigned)v.w << 16;
        a0 += c0.f; a1 += c1.f; a2 += c2.f; a3 += c3.f;
    };
    int i = s;
    for (; i + 4 <= e; i += 4) {
        ushort4 v0 = ((const ushort4*)(hsrc + (long)eidx[i] * 256))[lane];
        ushort4 v1 = ((const ushort4*)(hsrc + (long)eidx[i + 1] * 256))[lane];
        ushort4 v2 = ((const ushort4*)(hsrc + (long)eidx[i + 2] * 256))[lane];
        ushort4 v3 = ((const ushort4*)(hsrc + (long)eidx[i + 3] * 256))[lane];
        acc4(v0); acc4(v1); acc4(v2); acc4(v3);
    }
    for (; i < e; ++i) {
        ushort4 v = ((const ushort4*)(hsrc + (long)eidx[i] * 256))[lane];
        acc4(v);
    }
    int c = e - s; if (c < 1) c = 1;
    float sc = 1.f / (float)c;
    ushort4 o;
    o.x = f2bf(a0 * sc); o.y = f2bf(a1 * sc); o.z = f2bf(a2 * sc); o.w = f2bf(a3 * sc);
    *(ushort4*)(A + (long)w * 512 + lane * 4) = o;
    ushort4 sv = ((const ushort4*)(hsrc + (long)w * 256))[lane];
    *(ushort4*)(A + (long)w * 512 + 256 + lane * 4) = sv;
}

// ---------------- GEMM0: agg half via gload_lds, self half direct from x ----
// 512 thr (8 waves, 2x4), tile 128x256, K=512 in 16 steps of 32. (r7 version)
__global__ __launch_bounds__(512)
void k_gemm0(const u16* __restrict__ A0, const float* __restrict__ x,
             const u16* __restrict__ Bt, const float* __restrict__ bias,
             u16* __restrict__ outp) {
    __shared__ int4 Lbuf[2 * 30720 / 16];
    char* L = (char*)Lbuf;
    const int tid = threadIdx.x;
    const int lane = tid & 63, wid = tid >> 6;
    const int wm = wid >> 2, wn = wid & 3;
    const long m0 = (long)blockIdx.x * 128;

    f32x4 acc[4][4];
#pragma unroll
    for (int i = 0; i < 4; ++i)
#pragma unroll
        for (int j = 0; j < 4; ++j) acc[i][j] = (f32x4){0.f, 0.f, 0.f, 0.f};

    const char* Abase = (const char*)A0 + m0 * ROWB;
    const char* Bbase = (const char*)Bt;
    const int srow = tid >> 2, scq = tid & 3;  // self-half reg-stage mapping

    auto stage = [&](int buf, int kt) {
        char* lb = L + buf * 30720;
        const char* gb = Bbase + (size_t)kt * (256 * ROWB);
        if (kt < 8) {
            const char* ga = Abase + (size_t)kt * ((size_t)N1pad * ROWB);
#pragma unroll
            for (int c0 = 0; c0 < 4; ++c0) {
                int c = wid + c0 * 8;
                if (c < 30) {
                    const char* g = (c < 10) ? (ga + c * 1024) : (gb + (c - 10) * 1024);
                    gload16(g + lane * 16, lb + c * 1024);
                }
            }
        } else {
#pragma unroll
            for (int c0 = 0; c0 < 3; ++c0) {
                int c = wid + c0 * 8;
                if (c < 20) gload16(gb + c * 1024 + lane * 16, lb + 10240 + c * 1024);
            }
            // self half: 128 rows x 32 f32 from x, convert to bf16, ds_write
            const f32x4* p =
                (const f32x4*)(x + (m0 + srow) * 256 + (kt - 8) * 32 + scq * 8);
            f32x4 v0 = p[0], v1 = p[1];
            ushort4 h0, h1;
            h0.x = f2bf(v0[0]); h0.y = f2bf(v0[1]); h0.z = f2bf(v0[2]); h0.w = f2bf(v0[3]);
            h1.x = f2bf(v1[0]); h1.y = f2bf(v1[1]); h1.z = f2bf(v1[2]); h1.w = f2bf(v1[3]);
            ushort4* d = (ushort4*)(lb + srow * ROWB + scq * 16);
            d[0] = h0; d[1] = h1;
        }
    };

    stage(0, 0);
    const int rr = lane & 15, gg = lane >> 4;
    for (int ks = 0; ks < 16; ++ks) {
        int cur = ks & 1;
        __syncthreads();  // buf[cur] staged (vmcnt+lgkm drained); buf[cur^1] free
        if (ks + 1 < 16) stage(cur ^ 1, ks + 1);  // overlaps MFMA below
        const char* lb = L + cur * 30720;
        short8 af[4], bv[4];
#pragma unroll
        for (int f = 0; f < 4; ++f) {
            af[f] = *(const short8*)(lb + (wm * 64 + f * 16 + rr) * ROWB + gg * 16);
            bv[f] = *(const short8*)(lb + 10240 + (wn * 64 + f * 16 + rr) * ROWB + gg * 16);
        }
#pragma unroll
        for (int i = 0; i < 4; ++i)
#pragma unroll
            for (int j = 0; j < 4; ++j)
                acc[i][j] =
                    __builtin_amdgcn_mfma_f32_16x16x32_bf16(af[i], bv[j], acc[i][j], 0, 0, 0);
    }

    // epilogue: bias + relu + bf16 store (D row=(lane>>4)*4+q, col=lane&15)
#pragma unroll
    for (int j = 0; j < 4; ++j) {
        int col = wn * 64 + j * 16 + rr;
        float bvl = bias[col];
#pragma unroll
        for (int i = 0; i < 4; ++i) {
            long row = m0 + wm * 64 + i * 16 + gg * 4;
#pragma unroll
            for (int q = 0; q < 4; ++q) {
                long r = row + q;
                if (r < N1c) {
                    float v = acc[i][j][q] + bvl;
                    v = v > 0.f ? v : 0.f;
                    outp[r * 256 + col] = f2bf(v);
                }
            }
        }
    }
}

// ---------------- GEMM1 + fused log_softmax -> d_out ------------------------
// 256 thr (4 waves 2x2), tile 128x128 (cols 64..127 are zero pad), K=512.
__global__ __launch_bounds__(256)
void k_gemm1(const u16* __restrict__ A, const u16* __restrict__ Bt,
             const float* __restrict__ bias, float* __restrict__ outp) {
    __shared__ u16 As[128 * 40];
    __shared__ u16 Bs[128 * 40];
    const int tid = threadIdx.x;
    const int lane = tid & 63, wid = tid >> 6;
    const int wm = wid >> 1, wn = wid & 1;
    const long m0 = (long)blockIdx.x * 128;
    const int sar = tid >> 1, sac = (tid & 1) * 16;

    f32x4 acc[4][4];
#pragma unroll
    for (int i = 0; i < 4; ++i)
#pragma unroll
        for (int j = 0; j < 4; ++j) acc[i][j] = (f32x4){0.f, 0.f, 0.f, 0.f};

    int4 ra[2]; int4 rb[2];
    auto load_tile = [&](int ks) {
        int k0 = ks * 32;
        const int4* p = (const int4*)(A + (m0 + sar) * 512 + k0 + sac);
        ra[0] = p[0]; ra[1] = p[1];
        const int4* q = (const int4*)(Bt + (long)sar * 512 + k0 + sac);
        rb[0] = q[0]; rb[1] = q[1];
    };
    auto write_tile = [&]() {
        int4* da = (int4*)(As + sar * 40 + sac);
        da[0] = ra[0]; da[1] = ra[1];
        int4* db = (int4*)(Bs + sar * 40 + sac);
        db[0] = rb[0]; db[1] = rb[1];
    };

    load_tile(0);
    for (int ks = 0; ks < 16; ++ks) {
        __syncthreads();
        write_tile();
        __syncthreads();
        if (ks + 1 < 16) load_tile(ks + 1);
        short8 af[4], bv[4];
        const int rr = lane & 15, gg = lane >> 4;
#pragma unroll
        for (int f = 0; f < 4; ++f) {
            af[f] = *(const short8*)(As + (wm * 64 + f * 16 + rr) * 40 + gg * 8);
            bv[f] = *(const short8*)(Bs + (wn * 64 + f * 16 + rr) * 40 + gg * 8);
        }
#pragma unroll
        for (int i = 0; i < 4; ++i)
#pragma unroll
            for (int j = 0; j < 4; ++j)
                acc[i][j] =
                    __builtin_amdgcn_mfma_f32_16x16x32_bf16(af[i], bv[j], acc[i][j], 0, 0, 0);
    }

    // epilogue: only wn==0 waves hold real cols (0..63); bias + log_softmax
    const int rr = lane & 15, gg = lane >> 4;
    if (wn == 0) {
#pragma unroll
        for (int i = 0; i < 4; ++i) {
#pragma unroll
            for (int q = 0; q < 4; ++q) {
                long r = m0 + wm * 64 + i * 16 + gg * 4 + q;
                float v[4];
#pragma unroll
                for (int j = 0; j < 4; ++j) v[j] = acc[i][j][q] + bias[j * 16 + rr];
                float mx = fmaxf(fmaxf(v[0], v[1]), fmaxf(v[2], v[3]));
#pragma unroll
                for (int m = 1; m < 16; m <<= 1) mx = fmaxf(mx, __shfl_xor(mx, m, 16));
                float se = __expf(v[0] - mx) + __expf(v[1] - mx) +
                           __expf(v[2] - mx) + __expf(v[3] - mx);
#pragma unroll
                for (int m = 1; m < 16; m <<= 1) se += __shfl_xor(se, m, 16);
                float ln = __logf(se);
                if (r < N2c) {
#pragma unroll
                    for (int j = 0; j < 4; ++j)
                        outp[r * 64 + j * 16 + rr] = v[j] - mx - ln;
                }
            }
        }
    }
}

extern "C" void kernel_launch(void* const* d_in, const int* in_sizes, int n_in,
                              void* d_out, int out_size, void* d_ws, size_t ws_size,
                              hipStream_t stream) {
    const float* x   = (const float*)d_in[0];
    const int* src0  = (const int*)d_in[1];
    const int* dst0  = (const int*)d_in[2];
    const int* src1  = (const int*)d_in[3];
    const int* dst1  = (const int*)d_in[4];
    const float* Wl0 = (const float*)d_in[5];
    const float* b0  = (const float*)d_in[6];
    const float* Wr0 = (const float*)d_in[7];
    const float* Wl1 = (const float*)d_in[8];
    const float* b1  = (const float*)d_in[9];
    const float* Wr1 = (const float*)d_in[10];

    char* base = (char*)d_ws;
    size_t off = 0;
    auto alloc = [&](size_t bytes) -> void* {
        off = (off + 255) & ~(size_t)255;
        void* p = base + off;
        off += bytes;
        return p;
    };
    int* c0       = (int*)alloc((size_t)8 * N1c * 4);
    int* c1       = (int*)alloc((size_t)8 * N2c * 4);
    int* bs0      = (int*)alloc((size_t)8 * N1c * 4);
    int* bs1      = (int*)alloc((size_t)8 * N2c * 4);
    int* rs0      = (int*)alloc((size_t)(N1c + 1) * 4);
    int* rs1      = (int*)alloc((size_t)(N2c + 1) * 4);
    int* partials = (int*)alloc((size_t)(NB0 + NB1) * 4);
    int* eidx0    = (int*)alloc((size_t)E0c * 4);
    int* eidx1    = (int*)alloc((size_t)E1c * 4);
    u16* A0       = (u16*)alloc((size_t)8 * N1pad * ROWU * 2);   // agg half only
    u16* hbuf     = (u16*)alloc((size_t)N1pad * 256 * 2);
    u16* A1       = (u16*)alloc((size_t)N2pad * 512 * 2);
    u16* Bt0      = (u16*)alloc((size_t)16 * 256 * ROWU * 2);    // K-tiled
    u16* Bt1      = (u16*)alloc((size_t)128 * 512 * 2);

    (void)hipMemsetAsync(c0, 0, (size_t)8 * (N1c + N2c) * 4, stream);

    k_hist<<<HB + WCB, 256, 0, stream>>>(dst0, dst1, c0, c1,
                                         Bt0, Wl0, Wr0, Bt1, Wl1, Wr1);
    k_scanA<<<NB0 + NB1, 256, 0, stream>>>(c0, c1, partials);
    k_scanC<<<NB0 + NB1, 256, 0, stream>>>(c0, c1, partials, rs0, rs1, bs0, bs1);
    k_scat<<<HB, 256, 0, stream>>>(src0, dst0, src1, dst1,
                                   c0, c1, bs0, bs1, eidx0, eidx1);

    // layer 0: gather (agg half) then GEMM (self read direct from x)
    k_agg0<<<(N1c + 3) / 4, 256, 0, stream>>>(x, eidx0, rs0, A0, N1c);
    k_gemm0<<<N1pad / 128, 512, 0, stream>>>(A0, x, Bt0, b0, hbuf);

    // layer 1: gather then GEMM + fused log_softmax
    k_agg1<<<(N2c + 3) / 4, 256, 0, stream>>>(hbuf, eidx1, rs1, A1, N2c);
    k_gemm1<<<N2pad / 128, 256, 0, stream>>>(A1, Bt1, b1, (float*)d_out);
}